// Round 10
// baseline (7391.151 us; speedup 1.0000x reference)
//
#include <hip/hip_runtime.h>
#include <math.h>

typedef unsigned short u16;
typedef float f4v __attribute__((ext_vector_type(4)));
typedef __bf16 bfv8 __attribute__((ext_vector_type(8)));

#define MFMA16(a,b,c) __builtin_amdgcn_mfma_f32_16x16x32_bf16((a),(b),(c),0,0,0)

// ---------------- numeric helpers ----------------
__device__ __forceinline__ float bf2f(u16 x){
    unsigned int u = ((unsigned int)x) << 16;
    float f; __builtin_memcpy(&f, &u, 4); return f;
}
__device__ __forceinline__ u16 f2bf(float f){
    unsigned int u; __builtin_memcpy(&u, &f, 4);
    u += 0x7fffu + ((u >> 16) & 1u);
    return (u16)(u >> 16);
}
__device__ __forceinline__ float ldmix(const void* p, long i, int mode){
    if (mode) return ((const float*)p)[i];
    return bf2f(((const u16*)p)[i]);
}
__device__ __forceinline__ float sigf(float x){ return 1.0f/(1.0f+__expf(-x)); }
__device__ __forceinline__ float tanh_fast(float x){
    float e = __expf(2.0f*x);
    return 1.0f - 2.0f/(1.0f+e);
}

// ---------------- sizes ----------------
#define BATCH 256
#define TLEN 168
#define HOR 24

// ---------------- workspace layout (bytes) ----------------
#define OFF_FLAG 0ull
#define OFF_BAR  8ull            // grid-barrier counter (zeroed by k_init)
#define OFF_SENT 16ull
#define OFF_WF   256ull
#define OFF_UP   8721920ull
#define OFF_WP   9901568ull
#define OFF_DWP  10049024ull
#define OFF_DUP  11228672ull
#define OFF_H0   11621888ull
#define OFF_H1   11884032ull
#define OFF_C    12146176ull
#define OFF_Q    12932608ull     // 196608 f32 (q for 3 encoders)
#define OFF_SP   13719040ull
#define OFF_E    13981184ull
#define OFF_ENCOUT 17126912ull
#define OFF_PROJ 83187200ull
#define NEED_BYTES 149247488ull

#define W_ENCW 0
#define W_ENCU 73728
#define W_ENCB 663552
#define W_AW1  665856
#define W_AW2  862464
#define W_AV   1059072
#define W_DECW 1059840
#define W_DECU 1650432
#define W_DECB 1847040
#define W_EXTW 1847808
#define W_EXTB 1851904
#define W_O1W  1852160
#define W_O1B  2179840
#define W_O2W  2180096
#define W_O2B  2180352

__device__ const int c_wsz[15]  = {73728,589824,2304,196608,196608,768,590592,196608,768,4096,256,327680,256,256,1};
__device__ const int c_woff[15] = {W_ENCW,W_ENCU,W_ENCB,W_AW1,W_AW2,W_AV,W_DECW,W_DECU,W_DECB,W_EXTW,W_EXTB,W_O1W,W_O1B,W_O2W,W_O2B};

struct P15 { const void* p[15]; };

#define SENT_MAGIC 0x5AFE0000u
__device__ __forceinline__ void put_sent(char* ws, int idx){
    ((unsigned int*)(ws+OFF_SENT))[idx] = SENT_MAGIC | (unsigned int)idx;
}

// =========================================================================
__global__ __launch_bounds__(256) void k_probe(const u16* w16, char* ws)
{
    __shared__ float red[256];
    int tid = threadIdx.x;
    float mb = 0.0f;
    for (int i = tid; i < 2048; i += 256){
        float a = fabsf(bf2f(w16[i]));
        if (a > mb) mb = a;
    }
    red[tid] = mb;
    __syncthreads();
    if (tid == 0){
        for (int i = 1; i < 256; ++i) if (red[i] > mb) mb = red[i];
        *(int*)(ws+OFF_FLAG) = (mb > 1000.0f) ? 1 : 0;
        put_sent(ws, 0);
    }
}

// =========================================================================
__global__ __launch_bounds__(256) void k_convert(P15 in, char* ws)
{
    int mode = *(const int*)(ws+OFF_FLAG);
    float* F = (float*)(ws+OFF_WF);
    int y = blockIdx.y;
    int sz = c_wsz[y], off = c_woff[y];
    for (long i = (long)blockIdx.x*256 + threadIdx.x; i < sz; i += 256L*256L)
        F[off + i] = ldmix(in.p[y], i, mode);
    if (blockIdx.x==0 && blockIdx.y==0 && threadIdx.x==0) put_sent(ws, 1);
}

// =========================================================================
__global__ __launch_bounds__(64) void k_pack(char* ws)
{
    const float* F = (const float*)(ws+OFF_WF);
    int m = blockIdx.y;
    const float* src; u16* dst; int K, N;
    switch (m) {
      case 0: case 1: case 2:
        src = F + W_ENCU + m*196608; dst = (u16*)(ws+OFF_UP) + m*196608; K=256; N=768; break;
      case 3: case 4: case 5:
        src = F + W_ENCW + (m-3)*24576; dst = (u16*)(ws+OFF_WP) + (m-3)*24576; K=32; N=768; break;
      case 6:
        src = F + W_DECW; dst = (u16*)(ws+OFF_DWP); K=768; N=768; break;
      default:
        src = F + W_DECU; dst = (u16*)(ws+OFF_DUP); K=256; N=768; break;
    }
    int KT = K>>5, NT = N>>4;
    int tau = blockIdx.x;
    if (tau < KT*NT){
        int ct = tau / KT, kt = tau % KT;
        int l = threadIdx.x, q = l>>4, c = l&15;
        #pragma unroll
        for (int j = 0; j < 8; ++j)
            dst[((size_t)(ct*KT+kt)*64 + l)*8 + j] = f2bf(src[(size_t)(kt*32 + q*8 + j)*N + ct*16 + c]);
    }
    if (blockIdx.x==0 && blockIdx.y==0 && threadIdx.x==0) put_sent(ws, 6);
}

// =========================================================================
__global__ __launch_bounds__(256) void k_init(char* ws)
{
    long idx = (long)blockIdx.x*256 + threadIdx.x;
    if (idx < 65536) ((float*)(ws+OFF_H0))[idx] = 0.0f;
    else ((float*)(ws+OFF_C))[idx-65536] = 0.0f;
    if (blockIdx.x == 0 && threadIdx.x == 0)
        *(unsigned int*)(ws+OFF_BAR) = 0u;
}

// =========================================================================
// encoder GRU (MFMA): grid (8 rowtiles32, 3 encs), 512 thr (8 waves).
// 32 rows/block: each streamed B-fragment feeds 4 MFMAs (2 rowtiles x hi/lo)
// — 2x math per weight byte vs round-9. Split accumulator chains retained.
// =========================================================================
__global__ __launch_bounds__(512) void k_enc(const void* enc_in, char* ws, u16* enc_out)
{
    const float* F = (const float*)(ws+OFF_WF);
    int mode = *(const int*)(ws+OFF_FLAG);
    const int n  = blockIdx.y;
    const int b0 = blockIdx.x*32;
    const int tid = threadIdx.x;
    const int w = tid>>6, l = tid&63, quad = l>>4, c15 = l&15;

    __shared__ __align__(16) u16 hAhi[2][2][8][64][8];   // [buf][rt][kt][lane][8]
    __shared__ __align__(16) u16 hAlo[2][2][8][64][8];
    __shared__ __align__(16) u16 sx[2][64][8];

    {
        int* z0 = (int*)&hAhi[0][0][0][0][0];
        int* z1 = (int*)&hAlo[0][0][0][0][0];
        for (int i = tid; i < 8192; i += 512){ z0[i]=0; z1[i]=0; }
    }
    float h[16];
    #pragma unroll
    for (int i=0;i<16;++i) h[i]=0.0f;

    float bzr[2], brr[2], bnr[2];
    #pragma unroll
    for (int si=0;si<2;++si){
        int u = (w*2+si)*16 + c15;
        bzr[si] = F[W_ENCB + n*768 + u];
        brr[si] = F[W_ENCB + n*768 + 256 + u];
        bnr[si] = F[W_ENCB + n*768 + 512 + u];
    }
    __syncthreads();

    const u16* upn = (const u16*)(ws+OFF_UP) + n*196608;   // KT=8
    const u16* wpn = (const u16*)(ws+OFF_WP) + n*24576;    // KT=1

    for (int t = 0; t < TLEN; ++t){
        int p = t & 1;
        // stage x(t) for 32 rows as two K32 A-frag tiles
        for (int i = tid; i < 1024; i += 512){
            int m32 = i>>5, k = i&31;
            int rt = m32>>4, m = m32&15;
            sx[rt][(k>>3)*16 + m][k&7] =
                f2bf(ldmix(enc_in, (((long)(n*BATCH + b0 + m32))*TLEN + t)*32 + k, mode));
        }
        __syncthreads();

        bfv8 ah[2][8], al[2][8];
        #pragma unroll
        for (int rt=0; rt<2; ++rt)
            #pragma unroll
            for (int kt=0; kt<8; ++kt){
                ah[rt][kt] = *(const bfv8*)&hAhi[p][rt][kt][l][0];
                al[rt][kt] = *(const bfv8*)&hAlo[p][rt][kt][l][0];
            }
        bfv8 ax0 = *(const bfv8*)&sx[0][l][0];
        bfv8 ax1 = *(const bfv8*)&sx[1][l][0];

        #pragma unroll
        for (int si=0; si<2; ++si){
            int ct = w*2 + si;
            int ctz = ct, ctr = 16 + ct, ctn = 32 + ct;
            f4v azh[2], azl[2], arh[2], arl[2], anx[2], anhh[2], anhl[2];
            #pragma unroll
            for (int rt=0;rt<2;++rt){
                f4v zz = {0.f,0.f,0.f,0.f};
                azh[rt]=zz; azl[rt]=zz; arh[rt]=zz; arl[rt]=zz;
                anx[rt]=zz; anhh[rt]=zz; anhl[rt]=zz;
            }
            {
                bfv8 bw0 = *(const bfv8*)(wpn + ((size_t)ctz*64 + l)*8);
                bfv8 bw1 = *(const bfv8*)(wpn + ((size_t)ctr*64 + l)*8);
                bfv8 bw2 = *(const bfv8*)(wpn + ((size_t)ctn*64 + l)*8);
                azh[0] = MFMA16(ax0, bw0, azh[0]);  azh[1] = MFMA16(ax1, bw0, azh[1]);
                arh[0] = MFMA16(ax0, bw1, arh[0]);  arh[1] = MFMA16(ax1, bw1, arh[1]);
                anx[0] = MFMA16(ax0, bw2, anx[0]);  anx[1] = MFMA16(ax1, bw2, anx[1]);
            }
            #pragma unroll
            for (int kt=0; kt<8; ++kt){
                bfv8 bb = *(const bfv8*)(upn + ((size_t)(ctz*8+kt)*64 + l)*8);
                azh[0] = MFMA16(ah[0][kt], bb, azh[0]);
                azl[0] = MFMA16(al[0][kt], bb, azl[0]);
                azh[1] = MFMA16(ah[1][kt], bb, azh[1]);
                azl[1] = MFMA16(al[1][kt], bb, azl[1]);
            }
            #pragma unroll
            for (int kt=0; kt<8; ++kt){
                bfv8 bb = *(const bfv8*)(upn + ((size_t)(ctr*8+kt)*64 + l)*8);
                arh[0] = MFMA16(ah[0][kt], bb, arh[0]);
                arl[0] = MFMA16(al[0][kt], bb, arl[0]);
                arh[1] = MFMA16(ah[1][kt], bb, arh[1]);
                arl[1] = MFMA16(al[1][kt], bb, arl[1]);
            }
            #pragma unroll
            for (int kt=0; kt<8; ++kt){
                bfv8 bb = *(const bfv8*)(upn + ((size_t)(ctn*8+kt)*64 + l)*8);
                anhh[0] = MFMA16(ah[0][kt], bb, anhh[0]);
                anhl[0] = MFMA16(al[0][kt], bb, anhl[0]);
                anhh[1] = MFMA16(ah[1][kt], bb, anhh[1]);
                anhl[1] = MFMA16(al[1][kt], bb, anhl[1]);
            }
            int u = ct*16 + c15;
            #pragma unroll
            for (int rt=0; rt<2; ++rt){
                #pragma unroll
                for (int j=0;j<4;++j){
                    int m = quad*4 + j;
                    float z = sigf(azh[rt][j] + azl[rt][j] + bzr[si]);
                    float r = sigf(arh[rt][j] + arl[rt][j] + brr[si]);
                    float ng = tanh_fast(anx[rt][j] + bnr[si] + r*(anhh[rt][j] + anhl[rt][j]));
                    int hidx = rt*8 + si*4 + j;
                    float hn = (1.0f - z)*h[hidx] + z*ng;
                    h[hidx] = hn;
                    enc_out[(((long)(n*BATCH + b0 + rt*16 + m))*TLEN + t)*256 + u] = f2bf(hn);
                    u16 hi = f2bf(hn);
                    u16 lo = f2bf(hn - bf2f(hi));
                    int kt = u>>5, q2 = (u>>3)&3, j2 = u&7;
                    hAhi[1-p][rt][kt][q2*16+m][j2] = hi;
                    hAlo[1-p][rt][kt][q2*16+m][j2] = lo;
                }
            }
        }
        __syncthreads();
    }
    if (blockIdx.x==0 && blockIdx.y==0 && tid==0) put_sent(ws, 2);
}

// =========================================================================
// proj = enc_out @ att_W1[n] (VALU): grid (1344 rowtiles32, 3), 256 thr
// =========================================================================
__global__ __launch_bounds__(256) void k_proj(char* ws)
{
    const float* F = (const float*)(ws+OFF_WF);
    const u16* enc16 = (const u16*)(ws+OFF_ENCOUT);
    u16* proj = (u16*)(ws+OFF_PROJ);
    const int n = blockIdx.y;
    const long r0 = (long)blockIdx.x*32;
    const int tid = threadIdx.x;

    __shared__ float A[32][256];
    long base = ((long)n*43008 + r0)*256;
    for (int i = tid; i < 8192; i += 256)
        A[i>>8][i&255] = bf2f(enc16[base + i]);
    __syncthreads();

    const float* W1 = F + W_AW1 + n*65536;
    float acc[32];
    #pragma unroll
    for (int r = 0; r < 32; ++r) acc[r] = 0.0f;
    for (int k = 0; k < 256; ++k){
        float w = W1[k*256 + tid];
        #pragma unroll
        for (int r = 0; r < 32; ++r) acc[r] += A[r][k]*w;
    }
    for (int r = 0; r < 32; ++r)
        proj[base + (long)r*256 + tid] = f2bf(acc[r]);
    if (blockIdx.x==0 && blockIdx.y==0 && tid==0) put_sent(ws, 3);
}

// =========================================================================
// manual device-scope grid barrier (256 co-resident blocks)
// =========================================================================
__device__ __forceinline__ void gbar(unsigned int* cnt, unsigned int target, int tid)
{
    __syncthreads();
    if (tid == 0){
        __threadfence();
        atomicAdd(cnt, 1u);
        while (__hip_atomic_load(cnt, __ATOMIC_RELAXED, __HIP_MEMORY_SCOPE_AGENT) < target)
            __builtin_amdgcn_s_sleep(8);
        __threadfence();
    }
    __syncthreads();
}

// =========================================================================
// fused decoder: 24 steps in ONE regular launch, 256 blocks x 256 thr.
// Phase A: GRU gates (block = rowtile16 x uslice16, waves 0-2 = gates).
// Phase B: q = h @ W2 (blocks 0..95 = rowtile8 x n).
// Phase C: attention with parallel reductions (block = batch row, loop n).
// =========================================================================
__global__ __launch_bounds__(256) void k_dec_all(char* ws, const void* dec_in)
{
    const float* F = (const float*)(ws+OFF_WF);
    float* C = (float*)(ws+OFF_C);
    float* Q = (float*)(ws+OFF_Q);
    int mode = *(const int*)(ws+OFF_FLAG);
    const u16* dwp = (const u16*)(ws+OFF_DWP);
    const u16* dup = (const u16*)(ws+OFF_DUP);
    const u16* proj = (const u16*)(ws+OFF_PROJ);
    const u16* enc16 = (const u16*)(ws+OFF_ENCOUT);
    float* h0 = (float*)(ws+OFF_H0);
    float* h1 = (float*)(ws+OFF_H1);
    unsigned int* bar = (unsigned int*)(ws+OFF_BAR);

    const int blk = blockIdx.x;
    const int tid = threadIdx.x;
    const int gate = tid>>6, l = tid&63, quad = l>>4, c15 = l&15;
    const int rt = blk >> 4, us = blk & 15;
    const int b0 = rt*16, u0 = us*16;
    const int ct = gate*16 + us;

    __shared__ __align__(16) char smem[45056];
    // phase A views
    u16* aH = (u16*)smem;                       // [16][64][8] = 16384 B
    u16* aL = (u16*)(smem + 16384);             // 16384 B
    float* gz = (float*)(smem + 32768);         // 4 x [16][16]
    float* gr = gz + 256;
    float* gx = gr + 256;
    float* gh = gx + 256;
    // phase B view
    float* hB = (float*)smem;                   // [8][256] f32
    // phase C views
    float* ps = (float*)smem;                   // [168][65]
    float* sc = ps + 10920;                     // 168
    float* red = sc + 168;                      // 8

    unsigned int bt = 0;

    for (int s = 0; s < HOR; ++s){
        const float* h_in  = (s & 1) ? h1 : h0;
        float*       h_out = (s & 1) ? h0 : h1;

        // ---- phase A: GRU gates ----
        f4v accA = {0.f,0.f,0.f,0.f};
        f4v accAl = {0.f,0.f,0.f,0.f};
        f4v accB = {0.f,0.f,0.f,0.f};
        f4v accBl = {0.f,0.f,0.f,0.f};
        for (int half = 0; half < 2; ++half){
            __syncthreads();
            for (int e = tid; e < 8192; e += 256){
                int m = e>>9, kk = e&511;
                int kg = half*512 + kk;
                float v = (kg < 768) ? C[(long)(b0+m)*768 + kg]
                                     : h_in[(long)(b0+m)*256 + kg - 768];
                u16 hi = f2bf(v);
                u16 lo = f2bf(v - bf2f(hi));
                int ktl = kk>>5, q2 = (kk>>3)&3, j2 = kk&7;
                aH[(ktl*64 + q2*16+m)*8 + j2] = hi;
                aL[(ktl*64 + q2*16+m)*8 + j2] = lo;
            }
            __syncthreads();
            if (gate < 3){
                #pragma unroll
                for (int ktl = 0; ktl < 16; ++ktl){
                    int kg = half*16 + ktl;
                    const u16* bp = (kg < 24) ? dwp + ((size_t)(ct*24 + kg)*64 + l)*8
                                              : dup + ((size_t)(ct*8  + (kg-24))*64 + l)*8;
                    bfv8 bb = *(const bfv8*)bp;
                    bfv8 ah = *(const bfv8*)&aH[(ktl*64 + l)*8];
                    bfv8 al = *(const bfv8*)&aL[(ktl*64 + l)*8];
                    if (gate == 2 && kg >= 24){
                        accB  = MFMA16(ah, bb, accB);
                        accBl = MFMA16(al, bb, accBl);
                    } else {
                        accA  = MFMA16(ah, bb, accA);
                        accAl = MFMA16(al, bb, accAl);
                    }
                }
            }
        }
        if (gate < 3){
            #pragma unroll
            for (int j=0;j<4;++j){
                int m = quad*4 + j;
                float va = accA[j] + accAl[j];
                float vb = accB[j] + accBl[j];
                if (gate == 0) gz[m*16+c15] = va;
                else if (gate == 1) gr[m*16+c15] = va;
                else { gx[m*16+c15] = va; gh[m*16+c15] = vb; }
            }
        }
        __syncthreads();
        {
            int m = tid>>4, j = tid&15;
            int u = u0 + j;
            int b = b0 + m;
            float db = ldmix(dec_in, (long)b*HOR + s, mode);
            float sz = gz[m*16+j] + db*F[W_DECW + 768*768 + u]       + F[W_DECB + u];
            float sr = gr[m*16+j] + db*F[W_DECW + 768*768 + 256 + u] + F[W_DECB + 256 + u];
            float sn = gx[m*16+j] + db*F[W_DECW + 768*768 + 512 + u] + F[W_DECB + 512 + u];
            float z = sigf(sz);
            float r = sigf(sr);
            float ng = tanh_fast(sn + r*gh[m*16+j]);
            h_out[(long)b*256 + u] = (1.0f - z)*h_in[(long)b*256 + u] + z*ng;
        }
        gbar(bar, 256u*(++bt), tid);

        // ---- phase B: q = h_out @ W2 (blocks 0..95) ----
        if (blk < 96){
            int rb = blk / 3, n = blk % 3;
            for (int i = tid; i < 2048; i += 256)
                hB[i] = h_out[(long)(rb*8)*256 + i];
            __syncthreads();
            const float* W2 = F + W_AW2 + n*65536;
            float acc[8];
            #pragma unroll
            for (int r = 0; r < 8; ++r) acc[r] = 0.0f;
            for (int k = 0; k < 256; ++k){
                float wv = W2[(long)k*256 + tid];
                #pragma unroll
                for (int r = 0; r < 8; ++r) acc[r] += hB[r*256 + k]*wv;
            }
            for (int r = 0; r < 8; ++r)
                Q[(long)(n*BATCH + rb*8 + r)*256 + tid] = acc[r];
        }
        gbar(bar, 256u*(++bt), tid);

        // ---- phase C: attention (block = batch row), loop n ----
        {
            const int b = blk;
            for (int n = 0; n < 3; ++n){
                long base = ((long)n*43008 + (long)b*TLEN)*256;
                const u16* pb = proj + base;
                float qvr[4], vvr[4];
                #pragma unroll
                for (int c4=0;c4<4;++c4){
                    qvr[c4] = Q[(long)(n*BATCH + b)*256 + c4*64 + l];
                    vvr[c4] = F[W_AV + n*256 + c4*64 + l];
                }
                for (int i = 0; i < 42; ++i){
                    int t = gate*42 + i;
                    float sacc = 0.0f;
                    #pragma unroll
                    for (int c4=0;c4<4;++c4){
                        float pv = bf2f(pb[(long)t*256 + c4*64 + l]);
                        sacc += vvr[c4]*tanh_fast(pv + qvr[c4]);
                    }
                    ps[t*65 + l] = sacc;
                }
                __syncthreads();
                float sval = 0.0f;
                if (tid < TLEN){
                    float s0=0.f,s1=0.f,s2=0.f,s3=0.f,s4=0.f,s5=0.f,s6=0.f,s7=0.f;
                    #pragma unroll
                    for (int j = 0; j < 64; j += 8){
                        s0 += ps[tid*65+j];   s1 += ps[tid*65+j+1];
                        s2 += ps[tid*65+j+2]; s3 += ps[tid*65+j+3];
                        s4 += ps[tid*65+j+4]; s5 += ps[tid*65+j+5];
                        s6 += ps[tid*65+j+6]; s7 += ps[tid*65+j+7];
                    }
                    sval = ((s0+s1)+(s2+s3)) + ((s4+s5)+(s6+s7));
                }
                float m = (tid < TLEN) ? sval : -1e30f;
                #pragma unroll
                for (int off = 32; off > 0; off >>= 1) m = fmaxf(m, __shfl_xor(m, off, 64));
                if (l == 0) red[gate] = m;
                __syncthreads();
                float mx = fmaxf(fmaxf(red[0],red[1]), fmaxf(red[2],red[3]));
                float ex = 0.0f;
                if (tid < TLEN){ ex = __expf(sval - mx); sc[tid] = ex; }
                float su = ex;
                #pragma unroll
                for (int off = 32; off > 0; off >>= 1) su += __shfl_xor(su, off, 64);
                if (l == 0) red[4+gate] = su;
                __syncthreads();
                float inv = 1.0f/((red[4]+red[5]) + (red[6]+red[7]));
                const u16* eb = enc16 + base;
                float a0=0.f,a1=0.f,a2=0.f,a3=0.f,a4=0.f,a5=0.f,a6=0.f,a7=0.f;
                for (int t = 0; t < TLEN; t += 8){
                    a0 += sc[t  ]*bf2f(eb[(long)(t  )*256 + tid]);
                    a1 += sc[t+1]*bf2f(eb[(long)(t+1)*256 + tid]);
                    a2 += sc[t+2]*bf2f(eb[(long)(t+2)*256 + tid]);
                    a3 += sc[t+3]*bf2f(eb[(long)(t+3)*256 + tid]);
                    a4 += sc[t+4]*bf2f(eb[(long)(t+4)*256 + tid]);
                    a5 += sc[t+5]*bf2f(eb[(long)(t+5)*256 + tid]);
                    a6 += sc[t+6]*bf2f(eb[(long)(t+6)*256 + tid]);
                    a7 += sc[t+7]*bf2f(eb[(long)(t+7)*256 + tid]);
                }
                C[(long)b*768 + n*256 + tid] = (((a0+a1)+(a2+a3)) + ((a4+a5)+(a6+a7)))*inv;
                __syncthreads();
            }
        }
        gbar(bar, 256u*(++bt), tid);
    }
    if (blk == 0 && tid == 0) put_sent(ws, 4);
}

// =========================================================================
__global__ __launch_bounds__(256) void k_head1(char* ws, const float* h_last)
{
    const float* F = (const float*)(ws+OFF_WF);
    const float* C = (const float*)(ws+OFF_C);
    float* SP = (float*)(ws+OFF_SP);
    const int b0 = blockIdx.x*8;
    const int tid = threadIdx.x;

    __shared__ float A[8][1024];
    for (int i = tid; i < 8192; i += 256){
        int r = i >> 10, k = i & 1023;
        A[r][k] = (k < 256) ? h_last[(long)(b0+r)*256 + k]
                            : C[(long)(b0+r)*768 + (k-256)];
    }
    __syncthreads();

    const float* W = F + W_O1W;
    float acc[8];
    float bc = F[W_O1B + tid];
    #pragma unroll
    for (int r = 0; r < 8; ++r) acc[r] = bc;
    for (int k = 0; k < 1024; ++k){
        float w = W[k*256 + tid];
        #pragma unroll
        for (int r = 0; r < 8; ++r) acc[r] += A[r][k]*w;
    }
    for (int r = 0; r < 8; ++r)
        SP[(long)(b0+r)*256 + tid] = acc[r];
}

// =========================================================================
__global__ __launch_bounds__(256) void k_ext(const void* ext_feat, char* ws)
{
    const float* F = (const float*)(ws+OFF_WF);
    u16* E = (u16*)(ws+OFF_E);
    int mode = *(const int*)(ws+OFF_FLAG);
    const int r0 = blockIdx.x*64;
    const int tid = threadIdx.x;
    __shared__ float ef[64][16];
    for (int i = tid; i < 1024; i += 256)
        ef[i>>4][i&15] = ldmix(ext_feat, (long)(r0 + (i>>4))*16 + (i&15), mode);
    float wreg[16];
    #pragma unroll
    for (int k = 0; k < 16; ++k) wreg[k] = F[W_EXTW + k*256 + tid];
    float bb = F[W_EXTB + tid];
    __syncthreads();
    for (int r = 0; r < 64; ++r){
        float a = bb;
        #pragma unroll
        for (int k = 0; k < 16; ++k) a += ef[r][k]*wreg[k];
        E[(long)(r0+r)*256 + tid] = f2bf((a > 0.0f) ? a : 0.0f);
    }
}

// =========================================================================
__global__ __launch_bounds__(256) void k_head2(char* ws, void* out)
{
    const float* F = (const float*)(ws+OFF_WF);
    const u16* E = (const u16*)(ws+OFF_E);
    const float* SP = (const float*)(ws+OFF_SP);
    int mode = *(const int*)(ws+OFF_FLAG);
    const int r0 = blockIdx.x*16;
    const int tid = threadIdx.x;
    const int w = tid>>6, l = tid&63;

    __shared__ float A[16][256];
    __shared__ float x1[16][257];
    for (int i = tid; i < 4096; i += 256)
        A[i>>8][i&255] = bf2f(E[(long)r0*256 + i]);
    __syncthreads();

    const float* W = F + W_O1W + 1024*256;
    float acc[16];
    float bc = F[W_O1B + tid];
    #pragma unroll
    for (int r = 0; r < 16; ++r) acc[r] = 0.0f;
    for (int k = 0; k < 256; ++k){
        float wv = W[k*256 + tid];
        #pragma unroll
        for (int r = 0; r < 16; ++r) acc[r] += A[r][k]*wv;
    }
    for (int r = 0; r < 16; ++r){
        int g = r0 + r;
        int b = g / HOR;
        float v = acc[r] + SP[(long)b*256 + tid] + bc;
        x1[r][tid] = (v > 0.0f) ? v : 0.0f;
    }
    __syncthreads();

    float w2v[4];
    #pragma unroll
    for (int c4 = 0; c4 < 4; ++c4) w2v[c4] = F[W_O2W + c4*64 + l];
    float b2 = F[W_O2B];
    #pragma unroll
    for (int rr = 0; rr < 4; ++rr){
        int m = w*4 + rr;
        float s = 0.0f;
        #pragma unroll
        for (int c4 = 0; c4 < 4; ++c4) s += x1[m][c4*64 + l]*w2v[c4];
        for (int off = 32; off > 0; off >>= 1) s += __shfl_xor(s, off, 64);
        if (l == 0){
            float val = s + b2;
            long g = r0 + m;
            if (mode == 0) ((u16*)out)[g] = f2bf(val);
            else           ((float*)out)[g] = val;
        }
    }
    if (blockIdx.x==0 && tid==0) put_sent(ws, 5);
}

// =========================================================================
__global__ __launch_bounds__(64) void MTANet_7593502179851_kernel(char* ws, void* out)
{
    if (threadIdx.x == 0){
        const unsigned int* sent = (const unsigned int*)(ws+OFF_SENT);
        int mode = *(const int*)(ws+OFF_FLAG);
        for (int i = 0; i < 7; ++i){
            if (sent[i] != (SENT_MAGIC | (unsigned int)i)){
                float code = 400.0f + 10.0f*(float)i;
                if (mode == 0) ((u16*)out)[0] = f2bf(code);
                else           ((float*)out)[0] = code;
                break;
            }
        }
    }
}

__global__ __launch_bounds__(64) void k_diag(void* out, float code)
{
    if (threadIdx.x == 0){
        ((u16*)out)[0] = f2bf(code);
        ((float*)out)[1] = code;
    }
}

// =========================================================================
extern "C" void kernel_launch(void* const* d_in, const int* in_sizes, int n_in,
                              void* d_out, int out_size, void* d_ws, size_t ws_size,
                              hipStream_t stream)
{
    char* ws = (char*)d_ws;

    static const int exp_sizes[18] = {
        4128768, 6144, 98304, 73728, 589824, 2304, 196608, 196608, 768,
        590592, 196608, 768, 4096, 256, 327680, 256, 256, 1 };
    int bad_i = -1;
    if (n_in != 18) bad_i = 99;
    else for (int i = 0; i < 18; ++i)
        if (in_sizes[i] != exp_sizes[i]){ bad_i = i; break; }
    if (bad_i >= 0){
        k_diag<<<dim3(1), dim3(64), 0, stream>>>(d_out, 900.0f + (float)bad_i);
        return;
    }
    if (ws_size < (size_t)NEED_BYTES){
        k_diag<<<dim3(1), dim3(64), 0, stream>>>(d_out, 600.0f);
        return;
    }

    P15 wp;
    for (int i = 0; i < 15; ++i) wp.p[i] = d_in[3+i];

    hipError_t le[12];
    for (int i = 0; i < 12; ++i) le[i] = hipSuccess;
    (void)hipGetLastError();
    #define CHK(slot) { hipError_t e_ = hipGetLastError(); if (e_ != hipSuccess && le[slot] == hipSuccess) le[slot] = e_; }

    k_probe<<<dim3(1), dim3(256), 0, stream>>>((const u16*)d_in[3], ws);       CHK(0)
    k_convert<<<dim3(256,15), dim3(256), 0, stream>>>(wp, ws);                 CHK(1)
    k_pack<<<dim3(1152,8), dim3(64), 0, stream>>>(ws);                         CHK(2)
    k_init<<<dim3(1024), dim3(256), 0, stream>>>(ws);                          CHK(3)
    k_enc<<<dim3(8,3), dim3(512), 0, stream>>>(d_in[0], ws, (u16*)(ws+OFF_ENCOUT)); CHK(4)
    k_proj<<<dim3(1344,3), dim3(256), 0, stream>>>(ws);                        CHK(5)
    k_dec_all<<<dim3(256), dim3(256), 0, stream>>>(ws, d_in[1]);               CHK(6)
    k_head1<<<dim3(32), dim3(256), 0, stream>>>(ws, (float*)(ws+OFF_H0));      CHK(7)
    k_ext<<<dim3(96), dim3(256), 0, stream>>>(d_in[2], ws);                    CHK(8)
    k_head2<<<dim3(384), dim3(256), 0, stream>>>(ws, d_out);                   CHK(9)
    MTANet_7593502179851_kernel<<<dim3(1), dim3(64), 0, stream>>>(ws, d_out);  CHK(10)
    #undef CHK

    for (int i = 0; i < 12; ++i){
        if (le[i] != hipSuccess){
            k_diag<<<dim3(1), dim3(64), 0, stream>>>(d_out, 800.0f + (float)i);
            break;
        }
    }
}